// Round 3
// baseline (10167.946 us; speedup 1.0000x reference)
//
#include <hip/hip_runtime.h>
#include <math.h>

// B=4, T=32, N=32, F=16, GH=64, LH=128
#define T_STEPS 32
#define NNODES  32
#define FEAT    16
#define GHID    64
#define LSTM_IN 2048   // N*GH
#define LSTM_H  4096   // N*LH
#define GATES   16384  // 4*LSTM_H
#define BT      128    // B*T

typedef __attribute__((ext_vector_type(8))) short bhalf8;
typedef __attribute__((ext_vector_type(4))) float floatx4;

__device__ __forceinline__ float sigmoidf_(float x) { return 1.0f / (1.0f + __expf(-x)); }

__device__ __forceinline__ unsigned short f2bf(float f) {
    unsigned int u = __float_as_uint(f);
    u += 0x7FFFu + ((u >> 16) & 1u);
    return (unsigned short)(u >> 16);
}

// ---------------------------------------------------------------- zero init
__global__ void zero_f(float* p, int n) {
    int i = blockIdx.x * 256 + threadIdx.x;
    if (i < n) p[i] = 0.0f;
}

// ------------------------------------------------- fp32 -> bf16 bulk convert
__global__ void conv_bf16(const float* __restrict__ src, unsigned short* __restrict__ dst, int n4) {
    int i = blockIdx.x * 256 + threadIdx.x;
    if (i < n4) {
        float4 v = ((const float4*)src)[i];
        ushort4 o;
        o.x = f2bf(v.x); o.y = f2bf(v.y); o.z = f2bf(v.z); o.w = f2bf(v.w);
        ((ushort4*)dst)[i] = o;
    }
}

// ------------------------------------------------- dense normalized adjacency
__global__ void build_adj(const int* __restrict__ ei, int E, float* __restrict__ A) {
    __shared__ float As[NNODES * NNODES];
    __shared__ int   deg[NNODES];
    __shared__ float dinv[NNODES];
    int tid = threadIdx.x;
    if (tid < NNODES) deg[tid] = 1;
    for (int i = tid; i < NNODES * NNODES; i += 256) As[i] = 0.0f;
    __syncthreads();
    for (int e = tid; e < E; e += 256) atomicAdd(&deg[ei[E + e]], 1);
    __syncthreads();
    if (tid < NNODES) dinv[tid] = rsqrtf((float)deg[tid]);
    __syncthreads();
    for (int e = tid; e < E; e += 256) {
        int s = ei[e], d = ei[E + e];
        atomicAdd(&As[d * NNODES + s], dinv[s] * dinv[d]);
    }
    if (tid < NNODES) atomicAdd(&As[tid * NNODES + tid], dinv[tid] * dinv[tid]);
    __syncthreads();
    for (int i = tid; i < NNODES * NNODES; i += 256) A[i] = As[i];
}

// ------------------------------------------- LN + GCN1 + GCN2, one block/(b,t)
__global__ __launch_bounds__(256) void gcn2_kernel(
    const float* __restrict__ x, const float* __restrict__ ln_g, const float* __restrict__ ln_b,
    const float* __restrict__ W1, const float* __restrict__ b1,
    const float* __restrict__ W2, const float* __restrict__ b2,
    const float* __restrict__ A, float* __restrict__ seq)
{
    __shared__ float As[NNODES * NNODES];
    __shared__ float w1[FEAT * GHID];
    __shared__ float w2[GHID * GHID];
    __shared__ float xln[NNODES * FEAT];
    __shared__ float h1[NNODES * GHID];
    __shared__ float g1[NNODES * GHID];
    __shared__ float h2[NNODES * GHID];

    int tid = threadIdx.x;
    int bt = blockIdx.x;
    const float* xb = x + (size_t)bt * NNODES * FEAT;

    for (int i = tid; i < 1024; i += 256) As[i] = A[i];
    for (int i = tid; i < FEAT * GHID; i += 256) w1[i] = W1[i];
    for (int i = tid; i < GHID * GHID; i += 256) w2[i] = W2[i];
    for (int i = tid; i < NNODES * FEAT; i += 256) xln[i] = xb[i];
    __syncthreads();

    if (tid < NNODES) {
        float mu = 0.0f;
        for (int f = 0; f < FEAT; ++f) mu += xln[tid * FEAT + f];
        mu *= (1.0f / FEAT);
        float var = 0.0f;
        for (int f = 0; f < FEAT; ++f) { float d = xln[tid * FEAT + f] - mu; var += d * d; }
        var *= (1.0f / FEAT);
        float r = rsqrtf(var + 1e-5f);
        for (int f = 0; f < FEAT; ++f)
            xln[tid * FEAT + f] = (xln[tid * FEAT + f] - mu) * r * ln_g[f] + ln_b[f];
    }
    __syncthreads();

    for (int idx = tid; idx < NNODES * GHID; idx += 256) {
        int n = idx >> 6, j = idx & 63;
        float s = 0.0f;
        #pragma unroll
        for (int f = 0; f < FEAT; ++f) s += xln[n * FEAT + f] * w1[f * GHID + j];
        h1[idx] = s;
    }
    __syncthreads();
    for (int idx = tid; idx < NNODES * GHID; idx += 256) {
        int n = idx >> 6, j = idx & 63;
        float s = b1[j];
        #pragma unroll 8
        for (int m = 0; m < NNODES; ++m) s += As[n * NNODES + m] * h1[m * GHID + j];
        g1[idx] = s;
    }
    __syncthreads();
    for (int idx = tid; idx < NNODES * GHID; idx += 256) {
        int n = idx >> 6, j = idx & 63;
        float s = 0.0f;
        #pragma unroll 8
        for (int k = 0; k < GHID; ++k) s += g1[n * GHID + k] * w2[k * GHID + j];
        h2[idx] = s;
    }
    __syncthreads();
    for (int idx = tid; idx < NNODES * GHID; idx += 256) {
        int n = idx >> 6, j = idx & 63;
        float s = b2[j];
        #pragma unroll 8
        for (int m = 0; m < NNODES; ++m) s += As[n * NNODES + m] * h2[m * GHID + j];
        seq[(size_t)bt * LSTM_IN + idx] = s;
    }
}

// ---------------------------------- x_proj partials via MFMA, fused fp32->bf16
__global__ __launch_bounds__(256) void xproj_mfma(
    const float* __restrict__ seq, const float* __restrict__ W_ih,
    float* __restrict__ xpart)
{
    int lane = threadIdx.x & 63;
    int wid = blockIdx.x * 4 + (threadIdx.x >> 6);
    int ntile = wid >> 2;
    int kc = wid & 3;
    int n0 = ntile << 4;
    int rr = lane & 15;
    int kg = lane >> 4;

    floatx4 acc[8];
    #pragma unroll
    for (int mt = 0; mt < 8; ++mt) acc[mt] = (floatx4){0.f, 0.f, 0.f, 0.f};

    for (int ks = 0; ks < 16; ++ks) {
        int k0 = (kc << 9) + (ks << 5) + (kg << 3);
        const float4* wp = (const float4*)(W_ih + (size_t)(n0 + rr) * LSTM_IN + k0);
        float4 w0 = wp[0], w1 = wp[1];
        bhalf8 bf;
        bf[0] = (short)f2bf(w0.x); bf[1] = (short)f2bf(w0.y);
        bf[2] = (short)f2bf(w0.z); bf[3] = (short)f2bf(w0.w);
        bf[4] = (short)f2bf(w1.x); bf[5] = (short)f2bf(w1.y);
        bf[6] = (short)f2bf(w1.z); bf[7] = (short)f2bf(w1.w);
        #pragma unroll
        for (int mt = 0; mt < 8; ++mt) {
            const float4* ap = (const float4*)(seq + (size_t)(mt * 16 + rr) * LSTM_IN + k0);
            float4 a0 = ap[0], a1 = ap[1];
            bhalf8 af;
            af[0] = (short)f2bf(a0.x); af[1] = (short)f2bf(a0.y);
            af[2] = (short)f2bf(a0.z); af[3] = (short)f2bf(a0.w);
            af[4] = (short)f2bf(a1.x); af[5] = (short)f2bf(a1.y);
            af[6] = (short)f2bf(a1.z); af[7] = (short)f2bf(a1.w);
            acc[mt] = __builtin_amdgcn_mfma_f32_16x16x32_bf16(af, bf, acc[mt], 0, 0, 0);
        }
    }
    float* xo = xpart + (size_t)kc * (BT * GATES);
    #pragma unroll
    for (int mt = 0; mt < 8; ++mt) {
        #pragma unroll
        for (int i = 0; i < 4; ++i) {
            int row = mt * 16 + kg * 4 + i;
            xo[(size_t)row * GATES + n0 + rr] = acc[mt][i];
        }
    }
}

// -------------------------------- combine 4 K-partials + bias -> xp
__global__ void combine_xp(const float* __restrict__ xpart,
                           const float* __restrict__ b_ih, const float* __restrict__ b_hh,
                           float* __restrict__ xp)
{
    int i = blockIdx.x * 256 + threadIdx.x;
    const float4* p0 = (const float4*)xpart;
    const float4* p1 = p0 + (BT * GATES / 4);
    const float4* p2 = p1 + (BT * GATES / 4);
    const float4* p3 = p2 + (BT * GATES / 4);
    float4 a = p0[i], b = p1[i], c = p2[i], d = p3[i];
    int col = (i & (GATES / 4 - 1)) << 2;
    float4 o;
    o.x = a.x + b.x + c.x + d.x + b_ih[col + 0] + b_hh[col + 0];
    o.y = a.y + b.y + c.y + d.y + b_ih[col + 1] + b_hh[col + 1];
    o.z = a.z + b.z + c.z + d.z + b_ih[col + 2] + b_hh[col + 2];
    o.w = a.w + b.w + c.w + d.w + b_ih[col + 3] + b_hh[col + 3];
    ((float4*)xp)[i] = o;
}

// -------------------------------------------------- one LSTM time step (MFMA)
// 8192 waves. Wave W: ct = W>>3 (16 permuted cols: 4 gates x 4 j, j0=ct*4),
// kc = W&7 (K slice of 512). Last-of-8 wave per ct does the activation.
__global__ __launch_bounds__(256, 8) void lstm_step_mfma(
    const unsigned short* __restrict__ Wbf, const float* __restrict__ xp,
    const unsigned short* __restrict__ hin, unsigned short* __restrict__ hout,
    float* __restrict__ hf32, float* __restrict__ c,
    float* __restrict__ partial, int* __restrict__ cnt, int t)
{
    int lane = threadIdx.x & 63;
    int W = blockIdx.x * 4 + (threadIdx.x >> 6);   // 0..8191
    int ct = W >> 3;                                // 0..1023
    int kc = W & 7;                                 // 0..7
    int rr = lane & 15;
    int kg = lane >> 4;
    int j0 = ct << 2;

    int brow = ((rr >> 2) << 12) + j0 + (rr & 3);   // gate=rr>>2, j=j0+(rr&3)
    const unsigned short* bp = Wbf + ((size_t)brow << 12) + (kc << 9) + (kg << 3);
    const unsigned short* ap = hin + (rr << 12) + (kc << 9) + (kg << 3);
    bool arow = (rr < 4);

    floatx4 acc = (floatx4){0.f, 0.f, 0.f, 0.f};
    #pragma unroll
    for (int ks = 0; ks < 16; ++ks) {
        bhalf8 bf = *(const bhalf8*)(bp + ks * 32);
        bhalf8 af = {0, 0, 0, 0, 0, 0, 0, 0};
        if (arow) af = *(const bhalf8*)(ap + ks * 32);
        acc = __builtin_amdgcn_mfma_f32_16x16x32_bf16(af, bf, acc, 0, 0, 0);
    }

    // D: col=rr, row=kg*4+i -> batch rows 0-3 are in kg==0 lanes.
    if (kg == 0) {
        #pragma unroll
        for (int i = 0; i < 4; ++i)
            partial[kc * (4 * GATES) + i * GATES + (ct << 4) + rr] = acc[i];
    }
    __threadfence();
    int old = 0;
    if (lane == 0) old = atomicAdd(&cnt[ct], 1);
    old = __shfl(old, 0, 64);
    if (old == 7) {
        __threadfence();
        if (lane < 16) {
            int b = lane >> 2, ji = lane & 3;
            float pre[4];
            #pragma unroll
            for (int g = 0; g < 4; ++g) {
                float s = xp[(size_t)((b * T_STEPS + t) << 14) + (g << 12) + j0 + ji];
                #pragma unroll
                for (int k2 = 0; k2 < 8; ++k2)
                    s += partial[k2 * (4 * GATES) + b * GATES + (ct << 4) + (g << 2) + ji];
                pre[g] = s;
            }
            float gi = sigmoidf_(pre[0]);
            float gf = sigmoidf_(pre[1]);
            float gg = tanhf(pre[2]);
            float go = sigmoidf_(pre[3]);
            int hidx = (b << 12) + j0 + ji;
            float cn = gf * c[hidx] + gi * gg;
            float hn = go * tanhf(cn);
            c[hidx] = cn;
            hf32[hidx] = hn;
            hout[hidx] = f2bf(hn);
        }
    }
}

// -------------------------------------------------- final FC
__global__ void final_fc(const float* __restrict__ h, const float* __restrict__ fcW,
                         const float* __restrict__ fcb, float* __restrict__ out)
{
    int i = threadIdx.x;
    if (i < 128) {
        int b = i >> 5, n = i & 31;
        const float* hp = h + (size_t)b * LSTM_H + n * 128;
        float s = 0.0f;
        #pragma unroll 8
        for (int l = 0; l < 128; ++l) s += hp[l] * fcW[l];
        out[i] = s + fcb[0];
    }
}

extern "C" void kernel_launch(void* const* d_in, const int* in_sizes, int n_in,
                              void* d_out, int out_size, void* d_ws, size_t ws_size,
                              hipStream_t stream)
{
    const float* x    = (const float*)d_in[0];
    const int*   ei   = (const int*)d_in[1];
    const float* ln_g = (const float*)d_in[2];
    const float* ln_b = (const float*)d_in[3];
    const float* W1   = (const float*)d_in[4];
    const float* b1   = (const float*)d_in[5];
    const float* W2   = (const float*)d_in[6];
    const float* b2   = (const float*)d_in[7];
    const float* W_ih = (const float*)d_in[8];
    const float* b_ih = (const float*)d_in[9];
    const float* W_hh = (const float*)d_in[10];
    const float* b_hh = (const float*)d_in[11];
    const float* fcW  = (const float*)d_in[12];
    const float* fcb  = (const float*)d_in[13];
    int E = in_sizes[1] / 2;

    float* ws    = (float*)d_ws;
    float* A     = ws;                          // 1024
    float* seq   = A + 1024;                    // 262144
    float* xp    = seq + 262144;                // 2097152
    float* xpart = xp + 2097152;                // 8388608
    // --- zeroed region: c, hbf0, cnt (57344 floats) ---
    float* c     = xpart + 8388608;             // 16384
    float* hbf0f = c + 16384;                   // 8192 (ushort[16384])
    float* cntf  = hbf0f + 8192;                // 32768 (int[32768] = 32 steps x 1024)
    float* hbf1f = cntf + 32768;                // 8192
    float* hf32  = hbf1f + 8192;                // 16384
    float* part  = hf32 + 16384;                // 524288
    float* WbfF  = part + 524288;               // 33554432 (ushort[67108864])
    unsigned short* hbf0 = (unsigned short*)hbf0f;
    unsigned short* hbf1 = (unsigned short*)hbf1f;
    unsigned short* Wbf  = (unsigned short*)WbfF;
    int* cnt = (int*)cntf;

    zero_f<<<dim3(224), dim3(256), 0, stream>>>(c, 57344);
    build_adj<<<dim3(1), dim3(256), 0, stream>>>(ei, E, A);
    gcn2_kernel<<<dim3(BT), dim3(256), 0, stream>>>(x, ln_g, ln_b, W1, b1, W2, b2, A, seq);
    conv_bf16<<<dim3(65536), dim3(256), 0, stream>>>(W_hh, Wbf, GATES * LSTM_H / 4);
    xproj_mfma<<<dim3(1024), dim3(256), 0, stream>>>(seq, W_ih, xpart);
    combine_xp<<<dim3(2048), dim3(256), 0, stream>>>(xpart, b_ih, b_hh, xp);

    for (int t = 0; t < T_STEPS; ++t) {
        const unsigned short* hin = (t & 1) ? hbf1 : hbf0;
        unsigned short* hout      = (t & 1) ? hbf0 : hbf1;
        lstm_step_mfma<<<dim3(2048), dim3(256), 0, stream>>>(
            Wbf, xp, hin, hout, hf32, c, part, cnt + t * 1024, t);
    }
    final_fc<<<dim3(1), dim3(128), 0, stream>>>(hf32, fcW, fcb, (float*)d_out);
}

// Round 4
// 1427.395 us; speedup vs baseline: 7.1234x; 7.1234x over previous
//
#include <hip/hip_runtime.h>
#include <math.h>

// B=4, T=32, N=32, F=16, GH=64, LH=128
#define T_STEPS 32
#define NNODES  32
#define FEAT    16
#define GHID    64
#define LSTM_IN 2048   // N*GH
#define LSTM_H  4096   // N*LH
#define GATES   16384  // 4*LSTM_H
#define BT      128    // B*T

typedef __attribute__((ext_vector_type(8))) short bhalf8;
typedef __attribute__((ext_vector_type(4))) float floatx4;

__device__ __forceinline__ float sigmoidf_(float x) { return 1.0f / (1.0f + __expf(-x)); }

__device__ __forceinline__ unsigned short f2bf(float f) {
    unsigned int u = __float_as_uint(f);
    u += 0x7FFFu + ((u >> 16) & 1u);
    return (unsigned short)(u >> 16);
}

// ---------------------------------------------------------------- zero init
__global__ void zero_f(float* p, int n) {
    int i = blockIdx.x * 256 + threadIdx.x;
    if (i < n) p[i] = 0.0f;
}

// ------------------------------------------------- fp32 -> bf16 bulk convert
__global__ void conv_bf16(const float* __restrict__ src, unsigned short* __restrict__ dst, int n4) {
    int i = blockIdx.x * 256 + threadIdx.x;
    if (i < n4) {
        float4 v = ((const float4*)src)[i];
        ushort4 o;
        o.x = f2bf(v.x); o.y = f2bf(v.y); o.z = f2bf(v.z); o.w = f2bf(v.w);
        ((ushort4*)dst)[i] = o;
    }
}

// ------------------------------------------------- dense normalized adjacency
__global__ void build_adj(const int* __restrict__ ei, int E, float* __restrict__ A) {
    __shared__ float As[NNODES * NNODES];
    __shared__ int   deg[NNODES];
    __shared__ float dinv[NNODES];
    int tid = threadIdx.x;
    if (tid < NNODES) deg[tid] = 1;
    for (int i = tid; i < NNODES * NNODES; i += 256) As[i] = 0.0f;
    __syncthreads();
    for (int e = tid; e < E; e += 256) atomicAdd(&deg[ei[E + e]], 1);
    __syncthreads();
    if (tid < NNODES) dinv[tid] = rsqrtf((float)deg[tid]);
    __syncthreads();
    for (int e = tid; e < E; e += 256) {
        int s = ei[e], d = ei[E + e];
        atomicAdd(&As[d * NNODES + s], dinv[s] * dinv[d]);
    }
    if (tid < NNODES) atomicAdd(&As[tid * NNODES + tid], dinv[tid] * dinv[tid]);
    __syncthreads();
    for (int i = tid; i < NNODES * NNODES; i += 256) A[i] = As[i];
}

// ------------------------------------------- LN + GCN1 + GCN2, one block/(b,t)
__global__ __launch_bounds__(256) void gcn2_kernel(
    const float* __restrict__ x, const float* __restrict__ ln_g, const float* __restrict__ ln_b,
    const float* __restrict__ W1, const float* __restrict__ b1,
    const float* __restrict__ W2, const float* __restrict__ b2,
    const float* __restrict__ A, float* __restrict__ seq)
{
    __shared__ float As[NNODES * NNODES];
    __shared__ float w1[FEAT * GHID];
    __shared__ float w2[GHID * GHID];
    __shared__ float xln[NNODES * FEAT];
    __shared__ float h1[NNODES * GHID];
    __shared__ float g1[NNODES * GHID];
    __shared__ float h2[NNODES * GHID];

    int tid = threadIdx.x;
    int bt = blockIdx.x;
    const float* xb = x + (size_t)bt * NNODES * FEAT;

    for (int i = tid; i < 1024; i += 256) As[i] = A[i];
    for (int i = tid; i < FEAT * GHID; i += 256) w1[i] = W1[i];
    for (int i = tid; i < GHID * GHID; i += 256) w2[i] = W2[i];
    for (int i = tid; i < NNODES * FEAT; i += 256) xln[i] = xb[i];
    __syncthreads();

    if (tid < NNODES) {
        float mu = 0.0f;
        for (int f = 0; f < FEAT; ++f) mu += xln[tid * FEAT + f];
        mu *= (1.0f / FEAT);
        float var = 0.0f;
        for (int f = 0; f < FEAT; ++f) { float d = xln[tid * FEAT + f] - mu; var += d * d; }
        var *= (1.0f / FEAT);
        float r = rsqrtf(var + 1e-5f);
        for (int f = 0; f < FEAT; ++f)
            xln[tid * FEAT + f] = (xln[tid * FEAT + f] - mu) * r * ln_g[f] + ln_b[f];
    }
    __syncthreads();

    for (int idx = tid; idx < NNODES * GHID; idx += 256) {
        int n = idx >> 6, j = idx & 63;
        float s = 0.0f;
        #pragma unroll
        for (int f = 0; f < FEAT; ++f) s += xln[n * FEAT + f] * w1[f * GHID + j];
        h1[idx] = s;
    }
    __syncthreads();
    for (int idx = tid; idx < NNODES * GHID; idx += 256) {
        int n = idx >> 6, j = idx & 63;
        float s = b1[j];
        #pragma unroll 8
        for (int m = 0; m < NNODES; ++m) s += As[n * NNODES + m] * h1[m * GHID + j];
        g1[idx] = s;
    }
    __syncthreads();
    for (int idx = tid; idx < NNODES * GHID; idx += 256) {
        int n = idx >> 6, j = idx & 63;
        float s = 0.0f;
        #pragma unroll 8
        for (int k = 0; k < GHID; ++k) s += g1[n * GHID + k] * w2[k * GHID + j];
        h2[idx] = s;
    }
    __syncthreads();
    for (int idx = tid; idx < NNODES * GHID; idx += 256) {
        int n = idx >> 6, j = idx & 63;
        float s = b2[j];
        #pragma unroll 8
        for (int m = 0; m < NNODES; ++m) s += As[n * NNODES + m] * h2[m * GHID + j];
        seq[(size_t)bt * LSTM_IN + idx] = s;
    }
}

// ---------------------------------- x_proj partials via MFMA, fused fp32->bf16
__global__ __launch_bounds__(256) void xproj_mfma(
    const float* __restrict__ seq, const float* __restrict__ W_ih,
    float* __restrict__ xpart)
{
    int lane = threadIdx.x & 63;
    int wid = blockIdx.x * 4 + (threadIdx.x >> 6);
    int ntile = wid >> 2;
    int kc = wid & 3;
    int n0 = ntile << 4;
    int rr = lane & 15;
    int kg = lane >> 4;

    floatx4 acc[8];
    #pragma unroll
    for (int mt = 0; mt < 8; ++mt) acc[mt] = (floatx4){0.f, 0.f, 0.f, 0.f};

    for (int ks = 0; ks < 16; ++ks) {
        int k0 = (kc << 9) + (ks << 5) + (kg << 3);
        const float4* wp = (const float4*)(W_ih + (size_t)(n0 + rr) * LSTM_IN + k0);
        float4 w0 = wp[0], w1 = wp[1];
        bhalf8 bf;
        bf[0] = (short)f2bf(w0.x); bf[1] = (short)f2bf(w0.y);
        bf[2] = (short)f2bf(w0.z); bf[3] = (short)f2bf(w0.w);
        bf[4] = (short)f2bf(w1.x); bf[5] = (short)f2bf(w1.y);
        bf[6] = (short)f2bf(w1.z); bf[7] = (short)f2bf(w1.w);
        #pragma unroll
        for (int mt = 0; mt < 8; ++mt) {
            const float4* ap = (const float4*)(seq + (size_t)(mt * 16 + rr) * LSTM_IN + k0);
            float4 a0 = ap[0], a1 = ap[1];
            bhalf8 af;
            af[0] = (short)f2bf(a0.x); af[1] = (short)f2bf(a0.y);
            af[2] = (short)f2bf(a0.z); af[3] = (short)f2bf(a0.w);
            af[4] = (short)f2bf(a1.x); af[5] = (short)f2bf(a1.y);
            af[6] = (short)f2bf(a1.z); af[7] = (short)f2bf(a1.w);
            acc[mt] = __builtin_amdgcn_mfma_f32_16x16x32_bf16(af, bf, acc[mt], 0, 0, 0);
        }
    }
    float* xo = xpart + (size_t)kc * (BT * GATES);
    #pragma unroll
    for (int mt = 0; mt < 8; ++mt) {
        #pragma unroll
        for (int i = 0; i < 4; ++i) {
            int row = mt * 16 + kg * 4 + i;
            xo[(size_t)row * GATES + n0 + rr] = acc[mt][i];
        }
    }
}

// -------------------------------- combine 4 K-partials + bias -> xp
__global__ void combine_xp(const float* __restrict__ xpart,
                           const float* __restrict__ b_ih, const float* __restrict__ b_hh,
                           float* __restrict__ xp)
{
    int i = blockIdx.x * 256 + threadIdx.x;
    const float4* p0 = (const float4*)xpart;
    const float4* p1 = p0 + (BT * GATES / 4);
    const float4* p2 = p1 + (BT * GATES / 4);
    const float4* p3 = p2 + (BT * GATES / 4);
    float4 a = p0[i], b = p1[i], c = p2[i], d = p3[i];
    int col = (i & (GATES / 4 - 1)) << 2;
    float4 o;
    o.x = a.x + b.x + c.x + d.x + b_ih[col + 0] + b_hh[col + 0];
    o.y = a.y + b.y + c.y + d.y + b_ih[col + 1] + b_hh[col + 1];
    o.z = a.z + b.z + c.z + d.z + b_ih[col + 2] + b_hh[col + 2];
    o.w = a.w + b.w + c.w + d.w + b_ih[col + 3] + b_hh[col + 3];
    ((float4*)xp)[i] = o;
}

// -------------------------------------------------- one LSTM time step (MFMA)
// One block (4 waves) per 16-col tile ct (4 j's x 4 gates, permuted cols).
// Wave w takes K-quarter w (K=1024): 32 MFMA. Partials combined in LDS —
// NO device fences/atomics (round-3 post-mortem: per-wave __threadfence
// caused an L2 writeback storm, 69 MB HBM re-fetch per step, 400 us/step).
__global__ __launch_bounds__(256) void lstm_step_mfma(
    const unsigned short* __restrict__ Wbf, const float* __restrict__ xp,
    const unsigned short* __restrict__ hin, unsigned short* __restrict__ hout,
    float* __restrict__ hf32, float* __restrict__ c, int t)
{
    __shared__ float part[4][64];
    int lane = threadIdx.x & 63;
    int w = threadIdx.x >> 6;       // K-quarter
    int ct = blockIdx.x;            // 0..1023
    int rr = lane & 15;
    int kg = lane >> 4;
    int j0 = ct << 2;

    // permuted col rr: gate = rr>>2, j = j0 + (rr&3)
    int brow = ((rr >> 2) << 12) + j0 + (rr & 3);
    const unsigned short* bp = Wbf + ((size_t)brow << 12) + (w << 10) + (kg << 3);
    const unsigned short* ap = hin + (rr << 12) + (w << 10) + (kg << 3);
    bool arow = (rr < 4);

    floatx4 acc = (floatx4){0.f, 0.f, 0.f, 0.f};
    #pragma unroll
    for (int ks = 0; ks < 32; ++ks) {
        bhalf8 bf = *(const bhalf8*)(bp + ks * 32);
        bhalf8 af = {0, 0, 0, 0, 0, 0, 0, 0};
        if (arow) af = *(const bhalf8*)(ap + ks * 32);
        acc = __builtin_amdgcn_mfma_f32_16x16x32_bf16(af, bf, acc, 0, 0, 0);
    }

    // D: col=rr, row=kg*4+i. Batch rows 0-3 live in kg==0 lanes (lane==rr).
    if (kg == 0) {
        #pragma unroll
        for (int i = 0; i < 4; ++i) part[w][i * 16 + rr] = acc[i];
    }
    __syncthreads();

    if (threadIdx.x < 16) {
        int b = threadIdx.x >> 2, ji = threadIdx.x & 3;
        float pre[4];
        #pragma unroll
        for (int g = 0; g < 4; ++g) {
            int col = g * 4 + ji;
            float s = xp[(size_t)((b * T_STEPS + t) << 14) + (g << 12) + j0 + ji];
            #pragma unroll
            for (int k2 = 0; k2 < 4; ++k2) s += part[k2][b * 16 + col];
            pre[g] = s;
        }
        float gi = sigmoidf_(pre[0]);
        float gf = sigmoidf_(pre[1]);
        float gg = tanhf(pre[2]);
        float go = sigmoidf_(pre[3]);
        int hidx = (b << 12) + j0 + ji;
        float cn = gf * c[hidx] + gi * gg;
        float hn = go * tanhf(cn);
        c[hidx] = cn;
        hf32[hidx] = hn;
        hout[hidx] = f2bf(hn);
    }
}

// -------------------------------------------------- final FC
__global__ void final_fc(const float* __restrict__ h, const float* __restrict__ fcW,
                         const float* __restrict__ fcb, float* __restrict__ out)
{
    int i = threadIdx.x;
    if (i < 128) {
        int b = i >> 5, n = i & 31;
        const float* hp = h + (size_t)b * LSTM_H + n * 128;
        float s = 0.0f;
        #pragma unroll 8
        for (int l = 0; l < 128; ++l) s += hp[l] * fcW[l];
        out[i] = s + fcb[0];
    }
}

extern "C" void kernel_launch(void* const* d_in, const int* in_sizes, int n_in,
                              void* d_out, int out_size, void* d_ws, size_t ws_size,
                              hipStream_t stream)
{
    const float* x    = (const float*)d_in[0];
    const int*   ei   = (const int*)d_in[1];
    const float* ln_g = (const float*)d_in[2];
    const float* ln_b = (const float*)d_in[3];
    const float* W1   = (const float*)d_in[4];
    const float* b1   = (const float*)d_in[5];
    const float* W2   = (const float*)d_in[6];
    const float* b2   = (const float*)d_in[7];
    const float* W_ih = (const float*)d_in[8];
    const float* b_ih = (const float*)d_in[9];
    const float* W_hh = (const float*)d_in[10];
    const float* b_hh = (const float*)d_in[11];
    const float* fcW  = (const float*)d_in[12];
    const float* fcb  = (const float*)d_in[13];
    int E = in_sizes[1] / 2;

    float* ws    = (float*)d_ws;
    float* A     = ws;                          // 1024
    float* seq   = A + 1024;                    // 262144
    float* xp    = seq + 262144;                // 2097152
    float* xpart = xp + 2097152;                // 8388608
    // --- zeroed region: c, hbf0 (24576 floats) ---
    float* c     = xpart + 8388608;             // 16384
    float* hbf0f = c + 16384;                   // 8192 (ushort[16384])
    float* hbf1f = hbf0f + 8192;                // 8192
    float* hf32  = hbf1f + 8192;                // 16384
    float* WbfF  = hf32 + 16384;                // 33554432 (ushort[67108864])
    unsigned short* hbf0 = (unsigned short*)hbf0f;
    unsigned short* hbf1 = (unsigned short*)hbf1f;
    unsigned short* Wbf  = (unsigned short*)WbfF;

    zero_f<<<dim3(96), dim3(256), 0, stream>>>(c, 24576);
    build_adj<<<dim3(1), dim3(256), 0, stream>>>(ei, E, A);
    gcn2_kernel<<<dim3(BT), dim3(256), 0, stream>>>(x, ln_g, ln_b, W1, b1, W2, b2, A, seq);
    conv_bf16<<<dim3(65536), dim3(256), 0, stream>>>(W_hh, Wbf, GATES * LSTM_H / 4);
    xproj_mfma<<<dim3(1024), dim3(256), 0, stream>>>(seq, W_ih, xpart);
    combine_xp<<<dim3(2048), dim3(256), 0, stream>>>(xpart, b_ih, b_hh, xp);

    for (int t = 0; t < T_STEPS; ++t) {
        const unsigned short* hin = (t & 1) ? hbf1 : hbf0;
        unsigned short* hout      = (t & 1) ? hbf0 : hbf1;
        lstm_step_mfma<<<dim3(1024), dim3(256), 0, stream>>>(Wbf, xp, hin, hout, hf32, c, t);
    }
    final_fc<<<dim3(1), dim3(128), 0, stream>>>(hf32, fcW, fcb, (float*)d_out);
}